// Round 4
// baseline (375.298 us; speedup 1.0000x reference)
//
#include <hip/hip_runtime.h>

// VQ_68178310857191 — Lorentz VQ forward.
// d_in: [0] inputs_all (N x 65 f32), [1] lineages_all (N x 2 i32),
//       [2] embeddings (E x 64 f32), [3] genus_taxids_key (E i32)
// d_out: [0] mean_loss, [1 .. 1+N*65) quantized_all (f32)
// d_ws layout: int table[2E] | float cb[E*65] (c, qd[64] per entry) |
//              float loss[NBLOCKS] | float cnt[NBLOCKS]

#define NBLOCKS 2048
#define NTHREADS 256
#define WAVES_PER_BLOCK (NTHREADS / 64)

__device__ __forceinline__ float waveReduceSum(float v) {
#pragma unroll
    for (int m = 32; m >= 1; m >>= 1) v += __shfl_xor(v, m, 64);
    return v;
}

__device__ __forceinline__ float fast_tanh(float x) {
    x = fminf(fmaxf(x, -15.0f), 15.0f);
    float e2 = __expf(2.0f * x);
    return (e2 - 1.0f) * __builtin_amdgcn_rcpf(e2 + 1.0f);
}

// ---- taxid -> codebook index direct map ----
__global__ __launch_bounds__(256) void vq_table_init(int* __restrict__ table, int ts) {
    int i = blockIdx.x * 256 + threadIdx.x;
    if (i < ts) table[i] = -1;
}

__global__ __launch_bounds__(256) void vq_table_fill(const int* __restrict__ key,
                                                     int* __restrict__ table,
                                                     int E, int ts) {
    int i = blockIdx.x * 256 + threadIdx.x;
    if (i < E) {
        int k = key[i];
        if ((unsigned)k < (unsigned)ts) table[k] = i;
    }
}

// ---- precompute Lorentz-converted codebook: cb[e] = [cosh(n), sinh(n)/n * x] ----
__global__ __launch_bounds__(256) void vq_codebook(const float* __restrict__ emb,
                                                   float* __restrict__ cb, int E) {
    const int lane = threadIdx.x & 63;
    const int wave = (blockIdx.x * NTHREADS + threadIdx.x) >> 6;
    if (wave >= E) return;
    const float w = emb[(size_t)wave * 64 + lane];
    const float x = 3.0f * fast_tanh(w);
    float n2 = waveReduceSum(x * x);
    n2 = fmaxf(n2, 1e-6f);
    float n = fminf(sqrtf(n2), 10.0f);
    const float e  = __expf(n);
    const float ei = __builtin_amdgcn_rcpf(e);
    const float c  = 0.5f * (e + ei);
    const float s  = 0.5f * (e - ei) * __builtin_amdgcn_rcpf(n);
    float* cbRow = cb + (size_t)wave * 65;
    cbRow[1 + lane] = s * x;
    if (lane == 0) cbRow[0] = c;
}

// ---- main: per matched row, gather cb row, dot-reduce, dist; else copy ----
struct RowCtx {
    const float* inputs;
    const int*   lineages;
    const float* cb;
    const int*   table;
    float*       out;
    int          ts;
};

__device__ __forceinline__ void process_row(const RowCtx& c, int row, int lane,
                                            float& lossAcc, float& cntAcc) {
    const int t = c.lineages[2 * (size_t)row + 1];
    const int idx = ((unsigned)t < (unsigned)c.ts) ? c.table[t] : -1;

    const float* inRow = c.inputs + (size_t)row * 65;
    const float in0 = inRow[0];
    const float ind = inRow[1 + lane];
    float* outRow = c.out + 1 + (size_t)row * 65;

    if (idx >= 0) {                 // wave-uniform
        const float* cbRow = c.cb + (size_t)idx * 65;
        const float cc = cbRow[0];
        const float qd = cbRow[1 + lane];
        const float dot = waveReduceSum(qd * ind);
        const float lip = dot - cc * in0;
        const float z = fmaxf(-lip, 1.0f + 1e-6f);
        const float dist = __logf(z + sqrtf(fmaxf(z * z - 1.0f, 0.0f)));
        if (lane == 0) { lossAcc += 1.25f * dist; cntAcc += 1.0f; }
        outRow[1 + lane] = qd;
        if (lane == 0) outRow[0] = cc;
    } else {
        outRow[1 + lane] = ind;
        if (lane == 0) outRow[0] = in0;
    }
}

__global__ __launch_bounds__(NTHREADS) void vq_main(
    const float* __restrict__ inputs,
    const int*   __restrict__ lineages,
    const float* __restrict__ cb,
    const int*   __restrict__ table,
    float* __restrict__ out,
    float* __restrict__ partialLoss,
    float* __restrict__ partialCnt,
    int N, int ts)
{
    const int lane        = threadIdx.x & 63;
    const int waveInBlock = threadIdx.x >> 6;
    const int waveGlobal  = blockIdx.x * WAVES_PER_BLOCK + waveInBlock;
    const int totalWaves  = gridDim.x * WAVES_PER_BLOCK;
    const int half        = N >> 1;

    RowCtx c{inputs, lineages, cb, table, out, ts};
    float lossAcc = 0.0f, cntAcc = 0.0f;

    // two independent rows in flight per iteration (r and r+half)
    for (int row = waveGlobal; row < half; row += totalWaves) {
        process_row(c, row,        lane, lossAcc, cntAcc);
        process_row(c, row + half, lane, lossAcc, cntAcc);
    }

    __shared__ float sLoss[WAVES_PER_BLOCK];
    __shared__ float sCnt[WAVES_PER_BLOCK];
    if (lane == 0) { sLoss[waveInBlock] = lossAcc; sCnt[waveInBlock] = cntAcc; }
    __syncthreads();
    if (threadIdx.x == 0) {
        float L = 0.0f, C = 0.0f;
#pragma unroll
        for (int i = 0; i < WAVES_PER_BLOCK; i++) { L += sLoss[i]; C += sCnt[i]; }
        partialLoss[blockIdx.x] = L;
        partialCnt[blockIdx.x]  = C;
    }
}

__global__ __launch_bounds__(256) void vq_finalize(
    const float* __restrict__ partialLoss,
    const float* __restrict__ partialCnt,
    float* __restrict__ out, int nParts)
{
    __shared__ float sL[256];
    __shared__ float sC[256];
    float L = 0.0f, C = 0.0f;
    for (int i = threadIdx.x; i < nParts; i += 256) {
        L += partialLoss[i];
        C += partialCnt[i];
    }
    sL[threadIdx.x] = L; sC[threadIdx.x] = C;
    __syncthreads();
    if (threadIdx.x == 0) {
        float tl = 0.0f, tc = 0.0f;
        for (int i = 0; i < 256; i++) { tl += sL[i]; tc += sC[i]; }
        out[0] = tl / fmaxf(tc, 1.0f);
    }
}

extern "C" void kernel_launch(void* const* d_in, const int* in_sizes, int n_in,
                              void* d_out, int out_size, void* d_ws, size_t ws_size,
                              hipStream_t stream) {
    const float* inputs   = (const float*)d_in[0];
    const int*   lineages = (const int*)d_in[1];
    const float* emb      = (const float*)d_in[2];
    const int*   key      = (const int*)d_in[3];
    const int E = in_sizes[3];
    const int N = in_sizes[0] / 65;
    const int ts = 2 * E;

    float* out = (float*)d_out;
    char*  ws  = (char*)d_ws;
    int*   table = (int*)ws;                      // ts ints
    float* cb    = (float*)(ws + (size_t)ts * sizeof(int));      // E*65 floats
    float* partialLoss = cb + (size_t)E * 65;     // NBLOCKS
    float* partialCnt  = partialLoss + NBLOCKS;   // NBLOCKS

    vq_table_init<<<(ts + 255) / 256, 256, 0, stream>>>(table, ts);
    vq_table_fill<<<(E + 255) / 256, 256, 0, stream>>>(key, table, E, ts);
    vq_codebook<<<(E * 64 + NTHREADS - 1) / NTHREADS, NTHREADS, 0, stream>>>(emb, cb, E);
    vq_main<<<NBLOCKS, NTHREADS, 0, stream>>>(inputs, lineages, cb, table,
                                              out, partialLoss, partialCnt, N, ts);
    vq_finalize<<<1, 256, 0, stream>>>(partialLoss, partialCnt, out, NBLOCKS);
}

// Round 5
// 319.378 us; speedup vs baseline: 1.1751x; 1.1751x over previous
//
#include <hip/hip_runtime.h>

// VQ_68178310857191 — Lorentz VQ forward.
// d_in: [0] inputs_all (N x 65 f32), [1] lineages_all (N x 2 i32),
//       [2] embeddings (E x 64 f32), [3] genus_taxids_key (E i32)
// d_out: [0] mean_loss, [1 .. 1+N*65) quantized_all (f32)
// d_ws layout: int table[2E] | float cb[E*65] (c, qd[64]) | float loss[NBLOCKS] | cnt[NBLOCKS]

#define NBLOCKS 2048
#define NTHREADS 256
#define WAVES_PER_BLOCK (NTHREADS / 64)
#define CHUNK 64

__device__ __forceinline__ float waveReduceSum(float v) {
#pragma unroll
    for (int m = 32; m >= 1; m >>= 1) v += __shfl_xor(v, m, 64);
    return v;
}

__device__ __forceinline__ float fast_tanh(float x) {
    x = fminf(fmaxf(x, -15.0f), 15.0f);
    float e2 = __expf(2.0f * x);
    return (e2 - 1.0f) * __builtin_amdgcn_rcpf(e2 + 1.0f);
}

__global__ __launch_bounds__(256) void vq_table_init(int* __restrict__ table, int ts) {
    int i = blockIdx.x * 256 + threadIdx.x;
    if (i < ts) table[i] = -1;
}

__global__ __launch_bounds__(256) void vq_table_fill(const int* __restrict__ key,
                                                     int* __restrict__ table,
                                                     int E, int ts) {
    int i = blockIdx.x * 256 + threadIdx.x;
    if (i < E) {
        int k = key[i];
        if ((unsigned)k < (unsigned)ts) table[k] = i;
    }
}

// cb[e] = [cosh(n), sinh(n)/n * x]  (Lorentz lift of 3*tanh(emb))
__global__ __launch_bounds__(256) void vq_codebook(const float* __restrict__ emb,
                                                   float* __restrict__ cb, int E) {
    const int lane = threadIdx.x & 63;
    const int wave = (blockIdx.x * NTHREADS + threadIdx.x) >> 6;
    if (wave >= E) return;
    const float w = emb[(size_t)wave * 64 + lane];
    const float x = 3.0f * fast_tanh(w);
    float n2 = waveReduceSum(x * x);
    n2 = fmaxf(n2, 1e-6f);
    float n = fminf(sqrtf(n2), 10.0f);
    const float e  = __expf(n);
    const float ei = __builtin_amdgcn_rcpf(e);
    const float c  = 0.5f * (e + ei);
    const float s  = 0.5f * (e - ei) * __builtin_amdgcn_rcpf(n);
    float* cbRow = cb + (size_t)wave * 65;
    cbRow[1 + lane] = s * x;
    if (lane == 0) cbRow[0] = c;
}

__global__ __launch_bounds__(NTHREADS) void vq_main(
    const float* __restrict__ inputs,   // N x 65
    const int*   __restrict__ lineages, // N x 2
    const float* __restrict__ cb,       // E x 65
    const int*   __restrict__ table,    // ts, -1 = no match
    float* __restrict__ out,            // 1 + N*65
    float* __restrict__ partialLoss,
    float* __restrict__ partialCnt,
    int N, int ts)
{
    const int lane        = threadIdx.x & 63;
    const int waveInBlock = threadIdx.x >> 6;
    const int waveGlobal  = blockIdx.x * WAVES_PER_BLOCK + waveInBlock;
    const int totalWaves  = gridDim.x * WAVES_PER_BLOCK;
    const int nChunks     = (N + CHUNK - 1) / CHUNK;

    float lossAcc = 0.0f, cntAcc = 0.0f;

    for (int chunk = waveGlobal; chunk < nChunks; chunk += totalWaves) {
        const int base = chunk * CHUNK;

        if (base + CHUNK <= N) {
            // ---- chunk prologue: 3 wave-wide loads serve all 64 rows ----
            const int myRow   = base + lane;
            const int   t_l   = lineages[2 * (size_t)myRow + 1];     // coalesced
            const float in0_l = inputs[(size_t)myRow * 65];          // 1 gather
            const int   idx_l = ((unsigned)t_l < (unsigned)ts) ? table[t_l] : -1; // 1 gather
            float c_l = in0_l;   // per-lane time component of row `lane` (default: copy)

#pragma unroll 8
            for (int j = 0; j < CHUNK; ++j) {
                const int   sidx    = __builtin_amdgcn_readlane(idx_l, j);
                const float in0     = __uint_as_float(
                    __builtin_amdgcn_readlane(__float_as_uint(in0_l), j));
                const bool  matched = sidx >= 0;                     // wave-uniform

                const float* cbRow = cb + (size_t)(matched ? sidx : 0) * 65;
                const float cc = cbRow[0];                           // uniform load
                const float qd = cbRow[1 + lane];
                const float* inRow = inputs + (size_t)(base + j) * 65;
                const float ind = inRow[1 + lane];

                const float dot = waveReduceSum(qd * ind);
                const float lip = dot - cc * in0;
                const float z   = fmaxf(-lip, 1.0f + 1e-6f);
                const float dist = __logf(z + sqrtf(fmaxf(z * z - 1.0f, 0.0f)));
                lossAcc += matched ? 1.25f * dist : 0.0f;
                cntAcc  += matched ? 1.0f : 0.0f;

                out[1 + (size_t)(base + j) * 65 + 1 + lane] = matched ? qd : ind;
                const float tc = matched ? cc : in0;
                c_l = (lane == j) ? tc : c_l;
            }
            // one scatter store writes all 64 time components
            out[1 + (size_t)myRow * 65] = c_l;
        } else {
            // tail chunk (not hit for N % 64 == 0) — simple guarded path
            for (int j = 0; j < CHUNK; ++j) {
                const int row = base + j;
                if (row >= N) break;
                const int t = lineages[2 * (size_t)row + 1];
                const int idx = ((unsigned)t < (unsigned)ts) ? table[t] : -1;
                const float* inRow = inputs + (size_t)row * 65;
                const float in0 = inRow[0];
                const float ind = inRow[1 + lane];
                float* outRow = out + 1 + (size_t)row * 65;
                if (idx >= 0) {
                    const float* cbRow = cb + (size_t)idx * 65;
                    const float cc = cbRow[0];
                    const float qd = cbRow[1 + lane];
                    const float dot = waveReduceSum(qd * ind);
                    const float z = fmaxf(-(dot - cc * in0), 1.0f + 1e-6f);
                    const float dist = __logf(z + sqrtf(fmaxf(z * z - 1.0f, 0.0f)));
                    if (lane == 0) { lossAcc += 1.25f * dist; cntAcc += 1.0f; }
                    lossAcc = __shfl(lossAcc, 0, 64);  // keep lanes consistent
                    cntAcc  = __shfl(cntAcc, 0, 64);
                    outRow[1 + lane] = qd;
                    if (lane == 0) outRow[0] = cc;
                } else {
                    outRow[1 + lane] = ind;
                    if (lane == 0) outRow[0] = in0;
                }
            }
        }
    }

    __shared__ float sLoss[WAVES_PER_BLOCK];
    __shared__ float sCnt[WAVES_PER_BLOCK];
    if (lane == 0) { sLoss[waveInBlock] = lossAcc; sCnt[waveInBlock] = cntAcc; }
    __syncthreads();
    if (threadIdx.x == 0) {
        float L = 0.0f, C = 0.0f;
#pragma unroll
        for (int i = 0; i < WAVES_PER_BLOCK; i++) { L += sLoss[i]; C += sCnt[i]; }
        partialLoss[blockIdx.x] = L;
        partialCnt[blockIdx.x]  = C;
    }
}

__global__ __launch_bounds__(256) void vq_finalize(
    const float* __restrict__ partialLoss,
    const float* __restrict__ partialCnt,
    float* __restrict__ out, int nParts)
{
    __shared__ float sL[256];
    __shared__ float sC[256];
    float L = 0.0f, C = 0.0f;
    for (int i = threadIdx.x; i < nParts; i += 256) {
        L += partialLoss[i];
        C += partialCnt[i];
    }
    sL[threadIdx.x] = L; sC[threadIdx.x] = C;
    __syncthreads();
    if (threadIdx.x == 0) {
        float tl = 0.0f, tc = 0.0f;
        for (int i = 0; i < 256; i++) { tl += sL[i]; tc += sC[i]; }
        out[0] = tl / fmaxf(tc, 1.0f);
    }
}

extern "C" void kernel_launch(void* const* d_in, const int* in_sizes, int n_in,
                              void* d_out, int out_size, void* d_ws, size_t ws_size,
                              hipStream_t stream) {
    const float* inputs   = (const float*)d_in[0];
    const int*   lineages = (const int*)d_in[1];
    const float* emb      = (const float*)d_in[2];
    const int*   key      = (const int*)d_in[3];
    const int E = in_sizes[3];
    const int N = in_sizes[0] / 65;
    const int ts = 2 * E;

    float* out = (float*)d_out;
    char*  ws  = (char*)d_ws;
    int*   table = (int*)ws;                                     // ts ints
    float* cb    = (float*)(ws + (size_t)ts * sizeof(int));      // E*65 floats
    float* partialLoss = cb + (size_t)E * 65;
    float* partialCnt  = partialLoss + NBLOCKS;

    vq_table_init<<<(ts + 255) / 256, 256, 0, stream>>>(table, ts);
    vq_table_fill<<<(E + 255) / 256, 256, 0, stream>>>(key, table, E, ts);
    vq_codebook<<<(E * 64 + NTHREADS - 1) / NTHREADS, NTHREADS, 0, stream>>>(emb, cb, E);
    vq_main<<<NBLOCKS, NTHREADS, 0, stream>>>(inputs, lineages, cb, table,
                                              out, partialLoss, partialCnt, N, ts);
    vq_finalize<<<1, 256, 0, stream>>>(partialLoss, partialCnt, out, NBLOCKS);
}